// Round 21
// baseline (103.775 us; speedup 1.0000x reference)
//
#include <hip/hip_runtime.h>
#include <hip/hip_bf16.h>

// GCN 2-layer: out = Â·relu(Â·X·W0 + b0)·W1 + b1,  Â = D^-1/2 (A+I) D^-1/2
// GEMM-first, bf16 gather buffers, MFMA bf16 for layer-0 GEMM and aggmm h@W1,
// per-edge dinv gather weights (200KB L2 table), two-phase atomic-free CSR.
// R21: aggmm reshaped to an exact-resident grid — 1024 blocks (= 256 CU x 4
// blocks/CU, all co-resident, no scheduling tail), 49 nodes/block in two
// uniform rounds (25+24); W1t staged once per block.

typedef __attribute__((ext_vector_type(8))) unsigned short ushort8;
typedef __attribute__((ext_vector_type(8))) short short8;
typedef __attribute__((ext_vector_type(4))) float f32x4;

#define BUCKET 64   // per-node slots; Poisson(16) tail P(>63) ~ 1e-19
#define NBINS  196  // ceil(50000/256)
#define BINP   200  // padded stride for per-block goff tables (>= NBINS+1)
#define EPB    2048 // edges per scatter block
#define HP     136  // padded LDS row (bf16 elems): 272B rows, 16B-aligned
#define NPBLK  49   // aggmm nodes per block (1024 blocks x 49 >= 50000)
#define RND0   25   // aggmm round-0 node count (round 1 = 24)

__device__ inline float bf2f(unsigned short u) {
    return __uint_as_float(((unsigned)u) << 16);
}
__device__ inline unsigned short f2bf(float f) {
    unsigned u = __float_as_uint(f);
    return (unsigned short)((u + 0x7fffu + ((u >> 16) & 1u)) >> 16);  // RNE
}

// acc[i] += w * row[i]  (exact bf16->f32 via u32 pairs)
__device__ inline void fma8(float* acc, uint4 u, float w) {
    acc[0] = fmaf(w, __uint_as_float(u.x << 16), acc[0]);
    acc[1] = fmaf(w, __uint_as_float(u.x & 0xffff0000u), acc[1]);
    acc[2] = fmaf(w, __uint_as_float(u.y << 16), acc[2]);
    acc[3] = fmaf(w, __uint_as_float(u.y & 0xffff0000u), acc[3]);
    acc[4] = fmaf(w, __uint_as_float(u.z << 16), acc[4]);
    acc[5] = fmaf(w, __uint_as_float(u.z & 0xffff0000u), acc[5]);
    acc[6] = fmaf(w, __uint_as_float(u.w << 16), acc[6]);
    acc[7] = fmaf(w, __uint_as_float(u.w & 0xffff0000u), acc[7]);
}

// acc[i] += row[i]  (for pre-scaled HW' in agg64)
__device__ inline void acc8(float* acc, uint4 u) {
    acc[0] += __uint_as_float(u.x << 16);
    acc[1] += __uint_as_float(u.x & 0xffff0000u);
    acc[2] += __uint_as_float(u.y << 16);
    acc[3] += __uint_as_float(u.y & 0xffff0000u);
    acc[4] += __uint_as_float(u.z << 16);
    acc[5] += __uint_as_float(u.z & 0xffff0000u);
    acc[6] += __uint_as_float(u.w << 16);
    acc[7] += __uint_as_float(u.w & 0xffff0000u);
}

__device__ inline short8 pack8(float4 a, float4 b) {
    short8 r;
    r[0] = (short)f2bf(a.x); r[1] = (short)f2bf(a.y);
    r[2] = (short)f2bf(a.z); r[3] = (short)f2bf(a.w);
    r[4] = (short)f2bf(b.x); r[5] = (short)f2bf(b.y);
    r[6] = (short)f2bf(b.z); r[7] = (short)f2bf(b.w);
    return r;
}

// ---------------- pass A (fused): block-local bin sort + MFMA GEMM128 ----------------

__global__ __launch_bounds__(256) void k_fused0(
    const int* __restrict__ src, const int* __restrict__ dst,
    int* __restrict__ goff, unsigned* __restrict__ packed, int nE, int nSc,
    const float* __restrict__ A, const float* __restrict__ W,
    unsigned short* __restrict__ C, int n) {
    __shared__ __align__(16) char smem[24832];

    const int tx = threadIdx.x;

    if ((int)blockIdx.x < nSc) {
        int* hist    = (int*)smem;                  // 256 ints (200 used)
        int* woff    = (int*)(smem + 1024);         // 4 ints
        unsigned* lp = (unsigned*)(smem + 1040);    // 2048 uints (8KB)

        const int blk = blockIdx.x;
        const int elo = blk * EPB;
        const int ehi = min(nE, elo + EPB);
        const int ecnt = ehi - elo;

        hist[tx] = 0;
        __syncthreads();

        // load 8 edges; rank-from-hist atomic (arrival order within bin)
        int e0 = elo + tx * 8;
        int d[8], s[8], r[8];
        int cnt8 = 0;
        if (e0 + 7 < ehi) {
            int4 da = *reinterpret_cast<const int4*>(dst + e0);
            int4 db = *reinterpret_cast<const int4*>(dst + e0 + 4);
            int4 sa = *reinterpret_cast<const int4*>(src + e0);
            int4 sb = *reinterpret_cast<const int4*>(src + e0 + 4);
            d[0]=da.x; d[1]=da.y; d[2]=da.z; d[3]=da.w;
            d[4]=db.x; d[5]=db.y; d[6]=db.z; d[7]=db.w;
            s[0]=sa.x; s[1]=sa.y; s[2]=sa.z; s[3]=sa.w;
            s[4]=sb.x; s[5]=sb.y; s[6]=sb.z; s[7]=sb.w;
            cnt8 = 8;
        } else {
            for (int e = e0; e < ehi; ++e) { d[cnt8] = dst[e]; s[cnt8] = src[e]; ++cnt8; }
        }
#pragma unroll 8
        for (int q = 0; q < 8; ++q)
            if (q < cnt8) r[q] = atomicAdd(&hist[d[q] >> 8], 1);
        __syncthreads();

        // wave-level inclusive scan of hist[0..255] -> exclusive offsets
        const int lane = tx & 63;
        const int wv   = tx >> 6;
        int v = hist[tx];
        int sc = v;
#pragma unroll
        for (int o = 1; o < 64; o <<= 1) {
            int t = __shfl_up(sc, o);
            if (lane >= o) sc += t;
        }
        if (lane == 63) woff[wv] = sc;
        __syncthreads();
        int wo = 0;
        for (int k = 0; k < wv; ++k) wo += woff[k];
        int ex = sc + wo - v;                    // exclusive scan value
        if (tx <= NBINS) goff[blk * BINP + tx] = ex;   // tx==NBINS -> sentinel ecnt
        __syncthreads();                         // all v reads done
        hist[tx] = ex;                           // reuse hist as off2
        __syncthreads();

        // pack: pure LDS stores at off2[bin] + rank
#pragma unroll 8
        for (int q = 0; q < 8; ++q)
            if (q < cnt8)
                lp[hist[d[q] >> 8] + r[q]] = ((unsigned)(d[q] & 255) << 16) | (unsigned)s[q];
        __syncthreads();
        for (int i = tx; i < ecnt; i += 256) packed[elo + i] = lp[i];
        return;
    }

    // ---- MFMA GEMM path: C[n x 128](bf16) = bf16(A[n x 128]) @ bf16(W[128 x 128]) ----
    const int lane = tx & 63;
    const int w    = tx >> 6;
    const int lrow = lane & 15;
    const int kgrp = lane >> 4;          // 0..3
    const int row0 = ((int)blockIdx.x - nSc) * 64;
    const int colb = w * 32;

    f32x4 acc[2][4];
#pragma unroll
    for (int c = 0; c < 2; ++c)
#pragma unroll
        for (int rt = 0; rt < 4; ++rt)
            acc[c][rt] = (f32x4){0.f, 0.f, 0.f, 0.f};

#pragma unroll
    for (int kk = 0; kk < 4; ++kk) {
        const int kb = kk * 32 + kgrp * 8;
        short8 af[4];
#pragma unroll
        for (int rt = 0; rt < 4; ++rt) {
            int row = row0 + rt * 16 + lrow;
            float4 x0 = make_float4(0.f, 0.f, 0.f, 0.f);
            float4 x1 = make_float4(0.f, 0.f, 0.f, 0.f);
            if (row < n) {
                const float* p = A + (size_t)row * 128 + kb;
                x0 = *reinterpret_cast<const float4*>(p);
                x1 = *reinterpret_cast<const float4*>(p + 4);
            }
            af[rt] = pack8(x0, x1);
        }
        short8 bfr[2];
#pragma unroll
        for (int c = 0; c < 2; ++c) {
            int col = colb + c * 16 + lrow;
            const float* p = W + (size_t)kb * 128 + col;
            float4 wa, wb;
            wa.x = p[0 * 128]; wa.y = p[1 * 128]; wa.z = p[2 * 128]; wa.w = p[3 * 128];
            wb.x = p[4 * 128]; wb.y = p[5 * 128]; wb.z = p[6 * 128]; wb.w = p[7 * 128];
            bfr[c] = pack8(wa, wb);
        }
#pragma unroll
        for (int c = 0; c < 2; ++c)
#pragma unroll
            for (int rt = 0; rt < 4; ++rt)
                acc[c][rt] = __builtin_amdgcn_mfma_f32_16x16x32_bf16(
                    af[rt], bfr[c], acc[c][rt], 0, 0, 0);
    }

    // C/D layout: col = lane&15, row_in_tile = (lane>>4)*4 + r  [m89]
#pragma unroll
    for (int c = 0; c < 2; ++c) {
#pragma unroll
        for (int rt = 0; rt < 4; ++rt) {
#pragma unroll
            for (int r = 0; r < 4; ++r) {
                int row = row0 + rt * 16 + kgrp * 4 + r;
                if (row < n) {
                    int col = colb + c * 16 + lrow;
                    C[(size_t)row * 128 + col] = f2bf(acc[c][rt][r]);
                }
            }
        }
    }
}

// ---------------- pass B: per-bin bucket build (+ cnt/dinv tables) ----------------

__global__ __launch_bounds__(256) void k_binbuild(
    const unsigned* __restrict__ packed, const int* __restrict__ goff,
    int* __restrict__ cnt, float* __restrict__ dinv,
    unsigned short* __restrict__ col, int nSc, int n, int nE) {
    __shared__ int lcnt[256];
    __shared__ __align__(16) unsigned short lcol[256 * BUCKET];  // 32 KB
    const int b = blockIdx.x;
    const int t = threadIdx.x;
    lcnt[t] = 0;
    __syncthreads();

    for (int blk = t; blk < nSc; blk += 256) {
        int st = goff[blk * BINP + b];
        int c  = goff[blk * BINP + b + 1] - st;
        const unsigned* p = packed + (size_t)blk * EPB + st;
        for (int k = 0; k < c; ++k) {
            unsigned u = p[k];
            int dl = u >> 16;
            int r = atomicAdd(&lcnt[dl], 1);
            if (r < BUCKET) lcol[dl * BUCKET + r] = (unsigned short)u;
        }
    }
    __syncthreads();

    const int node0 = b * 256;
    uint4* g = reinterpret_cast<uint4*>(col + (size_t)node0 * BUCKET);
    const uint4* l = reinterpret_cast<const uint4*>(lcol);
    for (int i = t; i < 256 * BUCKET / 8; i += 256) g[i] = l[i];
    int node = node0 + t;
    if (node < n) {
        cnt[node]  = lcnt[t];
        dinv[node] = rsqrtf((float)lcnt[t] + 1.0f);
    }
}

// ---------------- fused layer-1 agg (dinv-weighted gather) + MFMA h@W1 ----------------
// LDS = hSb[32][HP] (8704) + W1t[64][HP] (17408) + diS (128) ≈ 25.6KB.
// R21: 1024 blocks exactly resident (4/CU); 49 nodes/block in rounds of 25+24.

__global__ __launch_bounds__(512) void k_aggmm(
    const unsigned short* __restrict__ V,   // XW bf16 [n][128] (unscaled)
    const int* __restrict__ cnt,
    const float* __restrict__ dinv,         // [n] f32, L2-resident
    const unsigned short* __restrict__ col,
    const float* __restrict__ b0v,          // [128]
    const float* __restrict__ W1,           // [128][64] f32
    unsigned short* __restrict__ HW,        // [n][64] bf16 (written pre-scaled)
    int n) {
    __shared__ __align__(16) unsigned short hSb[32 * HP];  // 8704 B
    __shared__ __align__(16) unsigned short W1t[64 * HP];  // 17408 B (transposed bf16)
    __shared__ float diS[32];
    const int tx = threadIdx.x;

    // stage W1 -> W1t once per block (bf16, transposed: W1t[c][k] = W1[k][c])
    for (int idx = tx; idx < 128 * 64; idx += 512) {
        int k = idx >> 6, c = idx & 63;
        W1t[c * HP + k] = f2bf(W1[idx]);
    }

    const int ln   = tx >> 4;
    const int d8   = (tx & 15) * 8;
    const int nb0  = (int)blockIdx.x * NPBLK;

    const int lane = tx & 63;
    const int w    = tx >> 6;
    const int rt   = w >> 2, ct = w & 3;
    const int lrow = lane & 15;
    const int kgrp = lane >> 4;

#pragma unroll
    for (int it = 0; it < 2; ++it) {
        const int base = nb0 + (it ? RND0 : 0);
        const int rcnt = it ? (NPBLK - RND0) : RND0;
        const int node = base + ln;

        if (it) __syncthreads();   // prev round's MFMA hSb reads complete

        if (ln < rcnt && node < n) {
            int degc = cnt[node];
            int deg = min(degc, BUCKET);
            float di = rsqrtf((float)degc + 1.0f);
            if ((tx & 15) == 0) diS[ln] = di;
            const unsigned short* cb = col + (size_t)node * BUCKET;
            float acc[8] = {};
            fma8(acc, *reinterpret_cast<const uint4*>(V + (size_t)node * 128 + d8), di);
            int j = 0;
            for (; j + 3 < deg; j += 4) {
                ushort4 c4 = *reinterpret_cast<const ushort4*>(cb + j);
                int s0 = c4.x, s1 = c4.y, s2 = c4.z, s3 = c4.w;
                float w0 = dinv[s0], w1 = dinv[s1], w2 = dinv[s2], w3 = dinv[s3];
                uint4 u0 = *reinterpret_cast<const uint4*>(V + (size_t)s0 * 128 + d8);
                uint4 u1 = *reinterpret_cast<const uint4*>(V + (size_t)s1 * 128 + d8);
                uint4 u2 = *reinterpret_cast<const uint4*>(V + (size_t)s2 * 128 + d8);
                uint4 u3 = *reinterpret_cast<const uint4*>(V + (size_t)s3 * 128 + d8);
                fma8(acc, u0, w0); fma8(acc, u1, w1);
                fma8(acc, u2, w2); fma8(acc, u3, w3);
            }
            for (; j < deg; ++j) {
                int si = cb[j];
                fma8(acc, *reinterpret_cast<const uint4*>(V + (size_t)si * 128 + d8), dinv[si]);
            }
#pragma unroll
            for (int i = 0; i < 8; ++i)
                hSb[ln * HP + d8 + i] = f2bf(fmaxf(di * acc[i] + b0v[d8 + i], 0.f));
        } else {
            if ((tx & 15) == 0) diS[ln] = 1.0f;
#pragma unroll
            for (int i = 0; i < 8; ++i) hSb[ln * HP + d8 + i] = 0;
        }
        __syncthreads();

        // MFMA phase: wave w -> tile (rt, ct); HW' = diS * (h @ W1)
        f32x4 acc2 = (f32x4){0.f, 0.f, 0.f, 0.f};
#pragma unroll
        for (int kk = 0; kk < 4; ++kk) {
            int ks = kk * 32 + kgrp * 8;
            short8 afr = *reinterpret_cast<const short8*>(hSb + (rt * 16 + lrow) * HP + ks);
            short8 bfr = *reinterpret_cast<const short8*>(W1t + (ct * 16 + lrow) * HP + ks);
            acc2 = __builtin_amdgcn_mfma_f32_16x16x32_bf16(afr, bfr, acc2, 0, 0, 0);
        }
#pragma unroll
        for (int r = 0; r < 4; ++r) {
            int lr = rt * 16 + kgrp * 4 + r;        // local row 0..31
            int node2 = base + lr;
            if (lr < rcnt && node2 < n) {
                int c = ct * 16 + lrow;
                HW[(size_t)node2 * 64 + c] = f2bf(diS[lr] * acc2[r]);
            }
        }
    }
}

// ---------------- final aggregation: out = di*(HW'[node] + Σ HW'[s]) + b1 ----------------

template <int DIM, bool RELU>
__global__ __launch_bounds__(256) void k_agg(const unsigned short* __restrict__ V,
                                             const int* __restrict__ cnt,
                                             const unsigned short* __restrict__ col,
                                             const float* __restrict__ bias,
                                             float* __restrict__ out, int n) {
    constexpr int TPN = DIM / 8;
    constexpr int NPBk = 256 / TPN;
    int node = blockIdx.x * NPBk + threadIdx.x / TPN;
    int d8 = (threadIdx.x % TPN) * 8;
    if (node >= n) return;
    int degc = cnt[node];
    int deg = min(degc, BUCKET);
    float di = rsqrtf((float)degc + 1.0f);
    const unsigned short* cb = col + (size_t)node * BUCKET;
    float acc[8] = {};
    acc8(acc, *reinterpret_cast<const uint4*>(V + (size_t)node * DIM + d8));
    int j = 0;
    for (; j + 3 < deg; j += 4) {
        ushort4 c4 = *reinterpret_cast<const ushort4*>(cb + j);
        int s0 = c4.x, s1 = c4.y, s2 = c4.z, s3 = c4.w;
        uint4 u0 = *reinterpret_cast<const uint4*>(V + (size_t)s0 * DIM + d8);
        uint4 u1 = *reinterpret_cast<const uint4*>(V + (size_t)s1 * DIM + d8);
        uint4 u2 = *reinterpret_cast<const uint4*>(V + (size_t)s2 * DIM + d8);
        uint4 u3 = *reinterpret_cast<const uint4*>(V + (size_t)s3 * DIM + d8);
        acc8(acc, u0); acc8(acc, u1); acc8(acc, u2); acc8(acc, u3);
    }
    for (; j < deg; ++j) {
        int si = cb[j];
        acc8(acc, *reinterpret_cast<const uint4*>(V + (size_t)si * DIM + d8));
    }
    float ob[8];
#pragma unroll
    for (int i = 0; i < 8; ++i) {
        float v = di * acc[i] + bias[d8 + i];
        ob[i] = RELU ? fmaxf(v, 0.f) : v;
    }
    float4* op = reinterpret_cast<float4*>(out + (size_t)node * DIM + d8);
    op[0] = make_float4(ob[0], ob[1], ob[2], ob[3]);
    op[1] = make_float4(ob[4], ob[5], ob[6], ob[7]);
}

// ---------------- launch ----------------

extern "C" void kernel_launch(void* const* d_in, const int* in_sizes, int n_in,
                              void* d_out, int out_size, void* d_ws, size_t ws_size,
                              hipStream_t stream) {
    const int n  = in_sizes[0];          // 50000 (< 65536: ushort cols)
    const int nE = in_sizes[1] / 2;      // 800000

    const int*   E  = (const int*)d_in[1];
    const float* X  = (const float*)d_in[2];
    const float* W0 = (const float*)d_in[3];
    const float* b0 = (const float*)d_in[4];
    const float* W1 = (const float*)d_in[5];
    const float* b1 = (const float*)d_in[6];
    float* out = (float*)d_out;

    const int* src = E;
    const int* dst = E + nE;

    const int nSc    = (nE + EPB - 1) / EPB;   // 391
    const int gGemm0 = (n + 63) / 64;          // 782
    const int gAgg   = (n + NPBLK - 1) / NPBLK; // 1021 (~exact-resident)

    char* ws = (char*)d_ws;
    int*            goff   = (int*)(ws + 0x000000);            // 313KB
    int*            cnt    = (int*)(ws + 0x050000);            // 200KB
    float*          dinv   = (float*)(ws + 0x084000);          // 200KB
    unsigned*       packed = (unsigned*)(ws + 0x0C0000);       // 3.2MB
    unsigned short* col    = (unsigned short*)(ws + 0x400000); // 6.42MB
    unsigned short* XW     = (unsigned short*)(ws + 0xA60000); // 12.8MB bf16
    unsigned short* HW     = (unsigned short*)(ws + 0x1760000);// 6.4MB bf16

    // pass A (fused): block-local bin sort (0..390) + MFMA layer-0 GEMM (391..1172)
    k_fused0<<<nSc + gGemm0, 256, 0, stream>>>(src, dst, goff, packed,
                                               nE, nSc, X, W0, XW, n);
    // pass B: per-bin bucket build + cnt/dinv tables
    k_binbuild<<<NBINS, 256, 0, stream>>>(packed, goff, cnt, dinv, col, nSc, n, nE);

    // fused: h = relu(di*(di*XW[node] + Σ dinv_s*XW[s]) + b0) in LDS; HW' = di*(h @ W1) [MFMA]
    k_aggmm<<<gAgg, 512, 0, stream>>>(XW, cnt, dinv, col, b0, W1, HW, n);

    // out = di*(HW'[node] + Σ HW'[s]) + b1
    k_agg<64, false><<<(n + 31) / 32, 256, 0, stream>>>(HW, cnt, col, b1, out, n);
}

// Round 22
// 95.022 us; speedup vs baseline: 1.0921x; 1.0921x over previous
//
#include <hip/hip_runtime.h>
#include <hip/hip_bf16.h>

// GCN 2-layer: out = Â·relu(Â·X·W0 + b0)·W1 + b1,  Â = D^-1/2 (A+I) D^-1/2
// GEMM-first, bf16 gather buffers, MFMA bf16 for layer-0 GEMM and aggmm h@W1,
// per-edge dinv gather weights (200KB L2 table).
// R22 = R20 verbatim (best measured 95.06µs). R21's exact-resident two-round
// aggmm regressed (intra-block round barriers beat inter-block scheduling).

typedef __attribute__((ext_vector_type(8))) unsigned short ushort8;
typedef __attribute__((ext_vector_type(8))) short short8;
typedef __attribute__((ext_vector_type(4))) float f32x4;

#define BUCKET 64   // per-node slots; Poisson(16) tail P(>63) ~ 1e-19
#define NBINS  196  // ceil(50000/256)
#define BINP   200  // padded stride for per-block goff tables (>= NBINS+1)
#define EPB    2048 // edges per scatter block
#define HP     136  // padded LDS row (bf16 elems): 272B rows, 16B-aligned

__device__ inline float bf2f(unsigned short u) {
    return __uint_as_float(((unsigned)u) << 16);
}
__device__ inline unsigned short f2bf(float f) {
    unsigned u = __float_as_uint(f);
    return (unsigned short)((u + 0x7fffu + ((u >> 16) & 1u)) >> 16);  // RNE
}

// acc[i] += w * row[i]  (exact bf16->f32 via u32 pairs)
__device__ inline void fma8(float* acc, uint4 u, float w) {
    acc[0] = fmaf(w, __uint_as_float(u.x << 16), acc[0]);
    acc[1] = fmaf(w, __uint_as_float(u.x & 0xffff0000u), acc[1]);
    acc[2] = fmaf(w, __uint_as_float(u.y << 16), acc[2]);
    acc[3] = fmaf(w, __uint_as_float(u.y & 0xffff0000u), acc[3]);
    acc[4] = fmaf(w, __uint_as_float(u.z << 16), acc[4]);
    acc[5] = fmaf(w, __uint_as_float(u.z & 0xffff0000u), acc[5]);
    acc[6] = fmaf(w, __uint_as_float(u.w << 16), acc[6]);
    acc[7] = fmaf(w, __uint_as_float(u.w & 0xffff0000u), acc[7]);
}

// acc[i] += row[i]  (for pre-scaled HW' in agg64)
__device__ inline void acc8(float* acc, uint4 u) {
    acc[0] += __uint_as_float(u.x << 16);
    acc[1] += __uint_as_float(u.x & 0xffff0000u);
    acc[2] += __uint_as_float(u.y << 16);
    acc[3] += __uint_as_float(u.y & 0xffff0000u);
    acc[4] += __uint_as_float(u.z << 16);
    acc[5] += __uint_as_float(u.z & 0xffff0000u);
    acc[6] += __uint_as_float(u.w << 16);
    acc[7] += __uint_as_float(u.w & 0xffff0000u);
}

__device__ inline short8 pack8(float4 a, float4 b) {
    short8 r;
    r[0] = (short)f2bf(a.x); r[1] = (short)f2bf(a.y);
    r[2] = (short)f2bf(a.z); r[3] = (short)f2bf(a.w);
    r[4] = (short)f2bf(b.x); r[5] = (short)f2bf(b.y);
    r[6] = (short)f2bf(b.z); r[7] = (short)f2bf(b.w);
    return r;
}

// ---------------- pass A (fused): block-local bin sort + MFMA GEMM128 ----------------

__global__ __launch_bounds__(256) void k_fused0(
    const int* __restrict__ src, const int* __restrict__ dst,
    int* __restrict__ goff, unsigned* __restrict__ packed, int nE, int nSc,
    const float* __restrict__ A, const float* __restrict__ W,
    unsigned short* __restrict__ C, int n) {
    __shared__ __align__(16) char smem[24832];

    const int tx = threadIdx.x;

    if ((int)blockIdx.x < nSc) {
        int* hist    = (int*)smem;                  // 256 ints (200 used)
        int* woff    = (int*)(smem + 1024);         // 4 ints
        unsigned* lp = (unsigned*)(smem + 1040);    // 2048 uints (8KB)

        const int blk = blockIdx.x;
        const int elo = blk * EPB;
        const int ehi = min(nE, elo + EPB);
        const int ecnt = ehi - elo;

        hist[tx] = 0;
        __syncthreads();

        // load 8 edges; rank-from-hist atomic (arrival order within bin)
        int e0 = elo + tx * 8;
        int d[8], s[8], r[8];
        int cnt8 = 0;
        if (e0 + 7 < ehi) {
            int4 da = *reinterpret_cast<const int4*>(dst + e0);
            int4 db = *reinterpret_cast<const int4*>(dst + e0 + 4);
            int4 sa = *reinterpret_cast<const int4*>(src + e0);
            int4 sb = *reinterpret_cast<const int4*>(src + e0 + 4);
            d[0]=da.x; d[1]=da.y; d[2]=da.z; d[3]=da.w;
            d[4]=db.x; d[5]=db.y; d[6]=db.z; d[7]=db.w;
            s[0]=sa.x; s[1]=sa.y; s[2]=sa.z; s[3]=sa.w;
            s[4]=sb.x; s[5]=sb.y; s[6]=sb.z; s[7]=sb.w;
            cnt8 = 8;
        } else {
            for (int e = e0; e < ehi; ++e) { d[cnt8] = dst[e]; s[cnt8] = src[e]; ++cnt8; }
        }
#pragma unroll 8
        for (int q = 0; q < 8; ++q)
            if (q < cnt8) r[q] = atomicAdd(&hist[d[q] >> 8], 1);
        __syncthreads();

        // wave-level inclusive scan of hist[0..255] -> exclusive offsets
        const int lane = tx & 63;
        const int wv   = tx >> 6;
        int v = hist[tx];
        int sc = v;
#pragma unroll
        for (int o = 1; o < 64; o <<= 1) {
            int t = __shfl_up(sc, o);
            if (lane >= o) sc += t;
        }
        if (lane == 63) woff[wv] = sc;
        __syncthreads();
        int wo = 0;
        for (int k = 0; k < wv; ++k) wo += woff[k];
        int ex = sc + wo - v;                    // exclusive scan value
        if (tx <= NBINS) goff[blk * BINP + tx] = ex;   // tx==NBINS -> sentinel ecnt
        __syncthreads();                         // all v reads done
        hist[tx] = ex;                           // reuse hist as off2
        __syncthreads();

        // pack: pure LDS stores at off2[bin] + rank
#pragma unroll 8
        for (int q = 0; q < 8; ++q)
            if (q < cnt8)
                lp[hist[d[q] >> 8] + r[q]] = ((unsigned)(d[q] & 255) << 16) | (unsigned)s[q];
        __syncthreads();
        for (int i = tx; i < ecnt; i += 256) packed[elo + i] = lp[i];
        return;
    }

    // ---- MFMA GEMM path: C[n x 128](bf16) = bf16(A[n x 128]) @ bf16(W[128 x 128]) ----
    const int lane = tx & 63;
    const int w    = tx >> 6;
    const int lrow = lane & 15;
    const int kgrp = lane >> 4;          // 0..3
    const int row0 = ((int)blockIdx.x - nSc) * 64;
    const int colb = w * 32;

    f32x4 acc[2][4];
#pragma unroll
    for (int c = 0; c < 2; ++c)
#pragma unroll
        for (int rt = 0; rt < 4; ++rt)
            acc[c][rt] = (f32x4){0.f, 0.f, 0.f, 0.f};

#pragma unroll
    for (int kk = 0; kk < 4; ++kk) {
        const int kb = kk * 32 + kgrp * 8;
        short8 af[4];
#pragma unroll
        for (int rt = 0; rt < 4; ++rt) {
            int row = row0 + rt * 16 + lrow;
            float4 x0 = make_float4(0.f, 0.f, 0.f, 0.f);
            float4 x1 = make_float4(0.f, 0.f, 0.f, 0.f);
            if (row < n) {
                const float* p = A + (size_t)row * 128 + kb;
                x0 = *reinterpret_cast<const float4*>(p);
                x1 = *reinterpret_cast<const float4*>(p + 4);
            }
            af[rt] = pack8(x0, x1);
        }
        short8 bfr[2];
#pragma unroll
        for (int c = 0; c < 2; ++c) {
            int col = colb + c * 16 + lrow;
            const float* p = W + (size_t)kb * 128 + col;
            float4 wa, wb;
            wa.x = p[0 * 128]; wa.y = p[1 * 128]; wa.z = p[2 * 128]; wa.w = p[3 * 128];
            wb.x = p[4 * 128]; wb.y = p[5 * 128]; wb.z = p[6 * 128]; wb.w = p[7 * 128];
            bfr[c] = pack8(wa, wb);
        }
#pragma unroll
        for (int c = 0; c < 2; ++c)
#pragma unroll
            for (int rt = 0; rt < 4; ++rt)
                acc[c][rt] = __builtin_amdgcn_mfma_f32_16x16x32_bf16(
                    af[rt], bfr[c], acc[c][rt], 0, 0, 0);
    }

    // C/D layout: col = lane&15, row_in_tile = (lane>>4)*4 + r  [m89]
#pragma unroll
    for (int c = 0; c < 2; ++c) {
#pragma unroll
        for (int rt = 0; rt < 4; ++rt) {
#pragma unroll
            for (int r = 0; r < 4; ++r) {
                int row = row0 + rt * 16 + kgrp * 4 + r;
                if (row < n) {
                    int col = colb + c * 16 + lrow;
                    C[(size_t)row * 128 + col] = f2bf(acc[c][rt][r]);
                }
            }
        }
    }
}

// ---------------- pass B: per-bin bucket build (+ cnt/dinv tables) ----------------

__global__ __launch_bounds__(256) void k_binbuild(
    const unsigned* __restrict__ packed, const int* __restrict__ goff,
    int* __restrict__ cnt, float* __restrict__ dinv,
    unsigned short* __restrict__ col, int nSc, int n, int nE) {
    __shared__ int lcnt[256];
    __shared__ __align__(16) unsigned short lcol[256 * BUCKET];  // 32 KB
    const int b = blockIdx.x;
    const int t = threadIdx.x;
    lcnt[t] = 0;
    __syncthreads();

    for (int blk = t; blk < nSc; blk += 256) {
        int st = goff[blk * BINP + b];
        int c  = goff[blk * BINP + b + 1] - st;
        const unsigned* p = packed + (size_t)blk * EPB + st;
        for (int k = 0; k < c; ++k) {
            unsigned u = p[k];
            int dl = u >> 16;
            int r = atomicAdd(&lcnt[dl], 1);
            if (r < BUCKET) lcol[dl * BUCKET + r] = (unsigned short)u;
        }
    }
    __syncthreads();

    const int node0 = b * 256;
    uint4* g = reinterpret_cast<uint4*>(col + (size_t)node0 * BUCKET);
    const uint4* l = reinterpret_cast<const uint4*>(lcol);
    for (int i = t; i < 256 * BUCKET / 8; i += 256) g[i] = l[i];
    int node = node0 + t;
    if (node < n) {
        cnt[node]  = lcnt[t];
        dinv[node] = rsqrtf((float)lcnt[t] + 1.0f);
    }
}

// ---------------- fused layer-1 agg (dinv-weighted gather) + MFMA h@W1 ----------------
// LDS = hSb[32][HP] (8704) + W1t[64][HP] (17408) + diS (128) ≈ 25.6KB.

__global__ __launch_bounds__(512) void k_aggmm(
    const unsigned short* __restrict__ V,   // XW bf16 [n][128] (unscaled)
    const int* __restrict__ cnt,
    const float* __restrict__ dinv,         // [n] f32, L2-resident
    const unsigned short* __restrict__ col,
    const float* __restrict__ b0v,          // [128]
    const float* __restrict__ W1,           // [128][64] f32
    unsigned short* __restrict__ HW,        // [n][64] bf16 (written pre-scaled)
    int n) {
    __shared__ __align__(16) unsigned short hSb[32 * HP];  // 8704 B
    __shared__ __align__(16) unsigned short W1t[64 * HP];  // 17408 B (transposed bf16)
    __shared__ float diS[32];
    const int tx = threadIdx.x;

    // stage W1 -> W1t (bf16, transposed: W1t[c][k] = W1[k][c])
    for (int idx = tx; idx < 128 * 64; idx += 512) {
        int k = idx >> 6, c = idx & 63;
        W1t[c * HP + k] = f2bf(W1[idx]);
    }

    const int ln   = tx >> 4;
    const int d8   = (tx & 15) * 8;
    const int node = blockIdx.x * 32 + ln;

    if (node < n) {
        int degc = cnt[node];
        int deg = min(degc, BUCKET);
        float di = rsqrtf((float)degc + 1.0f);
        if ((tx & 15) == 0) diS[ln] = di;
        const unsigned short* cb = col + (size_t)node * BUCKET;
        float acc[8] = {};
        fma8(acc, *reinterpret_cast<const uint4*>(V + (size_t)node * 128 + d8), di);
        int j = 0;
        for (; j + 3 < deg; j += 4) {
            ushort4 c4 = *reinterpret_cast<const ushort4*>(cb + j);
            int s0 = c4.x, s1 = c4.y, s2 = c4.z, s3 = c4.w;
            float w0 = dinv[s0], w1 = dinv[s1], w2 = dinv[s2], w3 = dinv[s3];
            uint4 u0 = *reinterpret_cast<const uint4*>(V + (size_t)s0 * 128 + d8);
            uint4 u1 = *reinterpret_cast<const uint4*>(V + (size_t)s1 * 128 + d8);
            uint4 u2 = *reinterpret_cast<const uint4*>(V + (size_t)s2 * 128 + d8);
            uint4 u3 = *reinterpret_cast<const uint4*>(V + (size_t)s3 * 128 + d8);
            fma8(acc, u0, w0); fma8(acc, u1, w1);
            fma8(acc, u2, w2); fma8(acc, u3, w3);
        }
        for (; j < deg; ++j) {
            int si = cb[j];
            fma8(acc, *reinterpret_cast<const uint4*>(V + (size_t)si * 128 + d8), dinv[si]);
        }
#pragma unroll
        for (int i = 0; i < 8; ++i)
            hSb[ln * HP + d8 + i] = f2bf(fmaxf(di * acc[i] + b0v[d8 + i], 0.f));
    } else {
        if ((tx & 15) == 0) diS[ln] = 1.0f;
#pragma unroll
        for (int i = 0; i < 8; ++i) hSb[ln * HP + d8 + i] = 0;
    }
    __syncthreads();

    // MFMA phase: wave w -> tile (rt = w>>2, ct = w&3); HW' = diS * (h @ W1)
    const int lane = tx & 63;
    const int w    = tx >> 6;
    const int rt   = w >> 2, ct = w & 3;
    const int lrow = lane & 15;
    const int kgrp = lane >> 4;
    f32x4 acc2 = (f32x4){0.f, 0.f, 0.f, 0.f};
#pragma unroll
    for (int kk = 0; kk < 4; ++kk) {
        int ks = kk * 32 + kgrp * 8;
        short8 afr = *reinterpret_cast<const short8*>(hSb + (rt * 16 + lrow) * HP + ks);
        short8 bfr = *reinterpret_cast<const short8*>(W1t + (ct * 16 + lrow) * HP + ks);
        acc2 = __builtin_amdgcn_mfma_f32_16x16x32_bf16(afr, bfr, acc2, 0, 0, 0);
    }
#pragma unroll
    for (int r = 0; r < 4; ++r) {
        int lr = rt * 16 + kgrp * 4 + r;        // local row 0..31
        int node2 = blockIdx.x * 32 + lr;
        if (node2 < n) {
            int c = ct * 16 + lrow;
            HW[(size_t)node2 * 64 + c] = f2bf(diS[lr] * acc2[r]);
        }
    }
}

// ---------------- final aggregation: out = di*(HW'[node] + Σ HW'[s]) + b1 ----------------

template <int DIM, bool RELU>
__global__ __launch_bounds__(256) void k_agg(const unsigned short* __restrict__ V,
                                             const int* __restrict__ cnt,
                                             const unsigned short* __restrict__ col,
                                             const float* __restrict__ bias,
                                             float* __restrict__ out, int n) {
    constexpr int TPN = DIM / 8;
    constexpr int NPBk = 256 / TPN;
    int node = blockIdx.x * NPBk + threadIdx.x / TPN;
    int d8 = (threadIdx.x % TPN) * 8;
    if (node >= n) return;
    int degc = cnt[node];
    int deg = min(degc, BUCKET);
    float di = rsqrtf((float)degc + 1.0f);
    const unsigned short* cb = col + (size_t)node * BUCKET;
    float acc[8] = {};
    acc8(acc, *reinterpret_cast<const uint4*>(V + (size_t)node * DIM + d8));
    int j = 0;
    for (; j + 3 < deg; j += 4) {
        ushort4 c4 = *reinterpret_cast<const ushort4*>(cb + j);
        int s0 = c4.x, s1 = c4.y, s2 = c4.z, s3 = c4.w;
        uint4 u0 = *reinterpret_cast<const uint4*>(V + (size_t)s0 * DIM + d8);
        uint4 u1 = *reinterpret_cast<const uint4*>(V + (size_t)s1 * DIM + d8);
        uint4 u2 = *reinterpret_cast<const uint4*>(V + (size_t)s2 * DIM + d8);
        uint4 u3 = *reinterpret_cast<const uint4*>(V + (size_t)s3 * DIM + d8);
        acc8(acc, u0); acc8(acc, u1); acc8(acc, u2); acc8(acc, u3);
    }
    for (; j < deg; ++j) {
        int si = cb[j];
        acc8(acc, *reinterpret_cast<const uint4*>(V + (size_t)si * DIM + d8));
    }
    float ob[8];
#pragma unroll
    for (int i = 0; i < 8; ++i) {
        float v = di * acc[i] + bias[d8 + i];
        ob[i] = RELU ? fmaxf(v, 0.f) : v;
    }
    float4* op = reinterpret_cast<float4*>(out + (size_t)node * DIM + d8);
    op[0] = make_float4(ob[0], ob[1], ob[2], ob[3]);
    op[1] = make_float4(ob[4], ob[5], ob[6], ob[7]);
}

// ---------------- launch ----------------

extern "C" void kernel_launch(void* const* d_in, const int* in_sizes, int n_in,
                              void* d_out, int out_size, void* d_ws, size_t ws_size,
                              hipStream_t stream) {
    const int n  = in_sizes[0];          // 50000 (< 65536: ushort cols)
    const int nE = in_sizes[1] / 2;      // 800000

    const int*   E  = (const int*)d_in[1];
    const float* X  = (const float*)d_in[2];
    const float* W0 = (const float*)d_in[3];
    const float* b0 = (const float*)d_in[4];
    const float* W1 = (const float*)d_in[5];
    const float* b1 = (const float*)d_in[6];
    float* out = (float*)d_out;

    const int* src = E;
    const int* dst = E + nE;

    const int nSc    = (nE + EPB - 1) / EPB;   // 391
    const int gGemm0 = (n + 63) / 64;          // 782

    char* ws = (char*)d_ws;
    int*            goff   = (int*)(ws + 0x000000);            // 313KB
    int*            cnt    = (int*)(ws + 0x050000);            // 200KB
    float*          dinv   = (float*)(ws + 0x084000);          // 200KB
    unsigned*       packed = (unsigned*)(ws + 0x0C0000);       // 3.2MB
    unsigned short* col    = (unsigned short*)(ws + 0x400000); // 6.42MB
    unsigned short* XW     = (unsigned short*)(ws + 0xA60000); // 12.8MB bf16
    unsigned short* HW     = (unsigned short*)(ws + 0x1760000);// 6.4MB bf16

    // pass A (fused): block-local bin sort (0..390) + MFMA layer-0 GEMM (391..1172)
    k_fused0<<<nSc + gGemm0, 256, 0, stream>>>(src, dst, goff, packed,
                                               nE, nSc, X, W0, XW, n);
    // pass B: per-bin bucket build + cnt/dinv tables
    k_binbuild<<<NBINS, 256, 0, stream>>>(packed, goff, cnt, dinv, col, nSc, n, nE);

    // fused: h = relu(di*(di*XW[node] + Σ dinv_s*XW[s]) + b0) in LDS; HW' = di*(h @ W1) [MFMA]
    k_aggmm<<<(n + 31) / 32, 512, 0, stream>>>(XW, cnt, dinv, col, b0, W1, HW, n);

    // out = di*(HW'[node] + Σ HW'[s]) + b1
    k_agg<64, false><<<(n + 31) / 32, 256, 0, stream>>>(HW, cnt, col, b1, out, n);
}